// Round 11
// baseline (520.923 us; speedup 1.0000x reference)
//
#include <hip/hip_runtime.h>
#include <hip/hip_bf16.h>

// MimiEuclideanCodebook — SINGLE bf16-MFMA scan with self-refining capture +
// np-bit-exact rescore + fused gather.
// scan: per (row, 128-col tile): 16-lane lex-min -> u64 atomicMin(rowmin);
//   capture codes with d2a <= min(tilemin, est)+DELTA where est comes from the
//   atomicMin RETURN (monotonically tightening global estimate). Superset proof
//   holds for ANY timing: est >= gm_final and tilemin >= gm_final, and
//   d2a(j*) <= gm_final + 2err <= gm_final + DELTA.
// rescore: filter stored (20-bit truncated fkey | code) by deq <= gm+DELTA
//   (floor-dequant <= actual => never drops j*), np-exact fp32 FMA-chain dot on
//   survivors, lex-(val,idx) min => output deterministic; junk only adds work.
// Fallback (cnt > SLOTS): full 2048-code exact scan (32 dots/lane, ~never).

typedef float f32x4 __attribute__((ext_vector_type(4)));
typedef short s16x4 __attribute__((ext_vector_type(4)));
typedef short s16x8 __attribute__((ext_vector_type(8)));

#define D_DIM 256
#define N_ROWS 65536
#define K_CODES 2048
#define VQ_EPS 1e-5f
#define DELTA 0.5f
#define SLOTS 96

__device__ __forceinline__ short bf16s(float f) {
    __hip_bfloat16 h = __float2bfloat16(f);
    return __builtin_bit_cast(short, h);
}
__device__ __forceinline__ unsigned fkey(float f) {       // order-preserving u32
    unsigned u = __float_as_uint(f);
    return (u & 0x80000000u) ? ~u : (u | 0x80000000u);
}
__device__ __forceinline__ float funkey(unsigned k) {
    unsigned u = (k & 0x80000000u) ? (k ^ 0x80000000u) : ~k;
    return __uint_as_float(u);
}

// ---------------- prep: embed = embed_sum / clip(usage) -----------------------
__global__ void prep_embed(const float* __restrict__ es, const float* __restrict__ us,
                           float* __restrict__ embed) {
    int i = blockIdx.x * 256 + threadIdx.x;               // 524288
    int k = i >> 8;
    float u = fmaxf(us[k], VQ_EPS);
    embed[i] = es[i] / u;                                 // IEEE div == np bitwise
}

// numpy pairwise sum of squares over 256 (verified round 4)
__device__ __forceinline__ void np_sumsq_16lane(const float* a, float* out, int g) {
#pragma clang fp contract(off)
    int j = g & 7, h = g >> 3;
    const float* p = a + h * 128;
    float t = p[j];
    float r = t * t;
#pragma unroll
    for (int i = 1; i < 16; ++i) { float v = p[j + 8 * i]; r += v * v; }
    r += __shfl_xor(r, 1);
    r += __shfl_xor(r, 2);
    r += __shfl_xor(r, 4);
    float other = __shfl_xor(r, 8);
    if (g == 0) *out = r + other;
}

__global__ void prep_e2(const float* __restrict__ embed, float* __restrict__ e2) {
    int gid = blockIdx.x * 256 + threadIdx.x;             // 2048 * 16
    int k = gid >> 4;
    np_sumsq_16lane(embed + k * D_DIM, e2 + k, threadIdx.x & 15);
}

__global__ void prep_x2(const float* __restrict__ x, float* __restrict__ x2,
                        unsigned long long* __restrict__ rowmin,
                        unsigned* __restrict__ counts) {
    int gid = blockIdx.x * 256 + threadIdx.x;             // 65536 * 16
    int r = gid >> 4;
    int g = threadIdx.x & 15;
    np_sumsq_16lane(x + r * D_DIM, x2 + r, g);
    if (g == 1) rowmin[r] = 0xFFFFFFFFFFFFFFFFull;
    if (g == 2) counts[r] = 0u;
}

// ---- single bf16 MFMA scan: rowmin atomic + self-refining capture ------------
__launch_bounds__(256, 2)
__global__ void vq_scan(const float* __restrict__ x, const float* __restrict__ embed,
                        const float* __restrict__ e2, const float* __restrict__ x2,
                        unsigned long long* __restrict__ rowmin,
                        unsigned* __restrict__ counts,
                        unsigned* __restrict__ cands) {
    __shared__ short lA[128][40];                         // bf16 bits, stride 40
    __shared__ short lB[128][40];

    const int bid = blockIdx.x;
    const int swz = (bid & 7) * 1024 + (bid >> 3);        // XCD-contiguous tiles
    const int mt = swz >> 4, nt = swz & 15;
    const int m_base = mt * 128, n_base = nt * 128;
    const int tid = threadIdx.x, lane = tid & 63, wid = tid >> 6;
    const int rb = wid * 32;                              // wave: rows rb..rb+31
    const int l15 = lane & 15, lg = lane >> 4;
    const int srow = tid >> 1, sseg = tid & 1;            // staging: row, 16-float half

    f32x4 acc[2][8];
#pragma unroll
    for (int m = 0; m < 2; ++m)
#pragma unroll
        for (int n = 0; n < 8; ++n) { f32x4 z = {0.f, 0.f, 0.f, 0.f}; acc[m][n] = z; }

    f32x4 rA[4], rB[4];
    auto gload = [&](int kc) {
#pragma unroll
        for (int v = 0; v < 4; ++v)
            rA[v] = *(const f32x4*)&x[(m_base + srow) * D_DIM + kc * 32 + sseg * 16 + v * 4];
#pragma unroll
        for (int v = 0; v < 4; ++v)
            rB[v] = *(const f32x4*)&embed[(n_base + srow) * D_DIM + kc * 32 + sseg * 16 + v * 4];
    };
    auto swrite = [&]() {
#pragma unroll
        for (int v = 0; v < 4; ++v) {
            s16x4 a, b;
#pragma unroll
            for (int j = 0; j < 4; ++j) { a[j] = bf16s(rA[v][j]); b[j] = bf16s(rB[v][j]); }
            *(s16x4*)&lA[srow][sseg * 16 + v * 4] = a;
            *(s16x4*)&lB[srow][sseg * 16 + v * 4] = b;
        }
    };
    auto compute = [&]() {
        s16x8 af[2], bf[8];
#pragma unroll
        for (int m = 0; m < 2; ++m)
            af[m] = *(const s16x8*)&lA[rb + m * 16 + l15][lg * 8];
#pragma unroll
        for (int n = 0; n < 8; ++n)
            bf[n] = *(const s16x8*)&lB[n * 16 + l15][lg * 8];
#pragma unroll
        for (int m = 0; m < 2; ++m)
#pragma unroll
            for (int n = 0; n < 8; ++n)
                acc[m][n] = __builtin_amdgcn_mfma_f32_16x16x32_bf16(af[m], bf[n], acc[m][n], 0, 0, 0);
    };

    gload(0);
#pragma unroll 1
    for (int kc = 0; kc < 8; ++kc) {
        __syncthreads();                                  // prev compute done
        swrite();
        __syncthreads();                                  // LDS visible
        if (kc < 7) gload(kc + 1);
        compute();
    }

    // epilogue: d2a = (x2 - 2*xe_a) + e2
    // C/D layout (rounds 8/10 verified): col = n*16 + l15, row = lg*4+j (+m*16)
    const int grow0 = m_base + rb + lg * 4;
    float e2v[8];
#pragma unroll
    for (int n = 0; n < 8; ++n) e2v[n] = e2[n_base + n * 16 + l15];

#pragma unroll
    for (int m = 0; m < 2; ++m) {
#pragma unroll
        for (int j = 0; j < 4; ++j) {
            int gr = grow0 + m * 16 + j;
            float x2v = x2[gr];
            float d2v[8];
            float bv = __builtin_inff(); int bc = 0x7FFFFFFF;
#pragma unroll
            for (int n = 0; n < 8; ++n) {
                d2v[n] = (x2v - 2.0f * acc[m][n][j]) + e2v[n];
                int code = n_base + n * 16 + l15;
                if (d2v[n] < bv) { bv = d2v[n]; bc = code; }  // ascending per lane
            }
#pragma unroll
            for (int s = 1; s < 16; s <<= 1) {            // 16-lane lex min
                float ov = __shfl_xor(bv, s);
                int oc = __shfl_xor(bc, s);
                if (ov < bv || (ov == bv && oc < bc)) { bv = ov; bc = oc; }
            }
            // bv = tilemin (uniform). atomicMin + read-back estimate.
            float est = bv;
            if (l15 == 0) {
                unsigned long long key =
                    ((unsigned long long)fkey(bv) << 32) | (unsigned)bc;
                unsigned long long old = atomicMin(&rowmin[gr], key);
                est = fminf(bv, funkey((unsigned)(old >> 32)));
            }
            est = __shfl(est, lane & 48);                 // group-base broadcast
            float cthr = est + DELTA;                     // est <= tilemin
#pragma unroll
            for (int n = 0; n < 8; ++n) {
                if (d2v[n] <= cthr) {
                    unsigned p = atomicAdd(&counts[gr], 1u);
                    if (p < SLOTS)
                        cands[gr * SLOTS + p] = (fkey(d2v[n]) & 0xFFFFF000u)
                                                | (unsigned)(n_base + n * 16 + l15);
                }
            }
        }
    }
}

// ------- np-exact rescore (wave per row) + fused gather -----------------------
__launch_bounds__(256, 4)
__global__ void vq_rescore(const float* __restrict__ x, const float* __restrict__ embed,
                           const float* __restrict__ e2, const float* __restrict__ x2,
                           const unsigned long long* __restrict__ rowmin,
                           const unsigned* __restrict__ counts,
                           const unsigned* __restrict__ cands,
                           const float* __restrict__ es, const float* __restrict__ us,
                           float* __restrict__ out) {
    const int tid = threadIdx.x, w = tid >> 6, lane = tid & 63;
    const int r = blockIdx.x * 4 + w;
    const unsigned cnt = counts[r];
    const float x2v = x2[r];
    const float thr = funkey((unsigned)(rowmin[r] >> 32)) + DELTA;

    float bv = __builtin_inff();
    int bi = 0x7FFFFFFF;

    auto dot_d2 = [&](int code) -> float {
        float t = 0.0f;
#pragma unroll 8
        for (int k4 = 0; k4 < 64; ++k4) {                 // single chain, k ascending
            f32x4 a4 = *(const f32x4*)&x[r * D_DIM + k4 * 4];   // wave-uniform
            f32x4 e4 = *(const f32x4*)&embed[code * D_DIM + k4 * 4];
            t = __builtin_fmaf(a4[0], e4[0], t);
            t = __builtin_fmaf(a4[1], e4[1], t);
            t = __builtin_fmaf(a4[2], e4[2], t);
            t = __builtin_fmaf(a4[3], e4[3], t);
        }
        return (x2v - 2.0f * t) + e2[code];               // np op order
    };
    auto lexmin = [&](float d2, int code) {
        if (d2 < bv || (d2 == bv && code < bi)) { bv = d2; bi = code; }
    };

    if (cnt <= SLOTS) {
        for (int idx = lane; idx < (int)cnt; idx += 64) {
            unsigned pk = cands[r * SLOTS + idx];
            float deq = funkey(pk & 0xFFFFF000u);         // lower bound of d2a
            if (deq <= thr) {                             // keeps j* provably
                int code = (int)(pk & 0x7FFu);
                lexmin(dot_d2(code), code);
            }
        }
    } else {
#pragma unroll 1
        for (int q = 0; q < 32; ++q) {                    // fallback: full exact scan
            int code = q * 64 + lane;
            lexmin(dot_d2(code), code);
        }
    }
#pragma unroll
    for (int s = 1; s < 64; s <<= 1) {                    // 64-lane lex allreduce
        float ov = __shfl_xor(bv, s);
        int oi = __shfl_xor(bi, s);
        if (ov < bv || (ov == bv && oi < bi)) { bv = ov; bi = oi; }
    }
    if (lane == 0) out[r] = (float)bi;

    // fused gather: quantized[r] = es[bi]/max(us[bi],eps); 64 lanes x 4 floats
    float u = fmaxf(us[bi], VQ_EPS);
    f32x4 wv = *(const f32x4*)&es[bi * D_DIM + lane * 4];
    f32x4 o;
#pragma unroll
    for (int j = 0; j < 4; ++j) o[j] = wv[j] / u;         // IEEE div == np bitwise
    *(f32x4*)&out[N_ROWS + r * D_DIM + lane * 4] = o;
}

extern "C" void kernel_launch(void* const* d_in, const int* in_sizes, int n_in,
                              void* d_out, int out_size, void* d_ws, size_t ws_size,
                              hipStream_t stream) {
    const float* x = (const float*)d_in[0];               // [65536, 256]
    const float* es = (const float*)d_in[1];              // [2048, 256]
    const float* us = (const float*)d_in[2];              // [2048]
    float* out = (float*)d_out;

    char* w = (char*)d_ws;                                // total 28,319,744 B
    float* embed          = (float*)(w);                  //  2,097,152
    float* e2             = (float*)(w + 2097152);        //      8,192
    float* x2             = (float*)(w + 2105344);        //    262,144
    unsigned long long* rowmin = (unsigned long long*)(w + 2367488); // 524,288
    unsigned* counts      = (unsigned*)(w + 2891776);     //    262,144
    unsigned* cands       = (unsigned*)(w + 3153920);     // 25,165,824 (SLOTS=96)

    hipLaunchKernelGGL(prep_embed, dim3(2048), dim3(256), 0, stream, es, us, embed);
    hipLaunchKernelGGL(prep_e2, dim3(128), dim3(256), 0, stream, embed, e2);
    hipLaunchKernelGGL(prep_x2, dim3(4096), dim3(256), 0, stream, x, x2, rowmin, counts);
    hipLaunchKernelGGL(vq_scan, dim3(8192), dim3(256), 0, stream,
                       x, embed, e2, x2, rowmin, counts, cands);
    hipLaunchKernelGGL(vq_rescore, dim3(16384), dim3(256), 0, stream,
                       x, embed, e2, x2, rowmin, counts, cands, es, us, out);
}

// Round 12
// 460.203 us; speedup vs baseline: 1.1319x; 1.1319x over previous
//
#include <hip/hip_runtime.h>
#include <hip/hip_bf16.h>

// MimiEuclideanCodebook — SINGLE bf16-MFMA scan (gload_lds staging, round-10
// proven) with top-2+cover epilogue (NO atomics, fully deterministic) +
// np-bit-exact rescore + fused gather.
// scan: per (row, 128-col tile) store key = trunc20(fkey(min1 d2a)) | code  and
//   cover = floorq(min2 - min1, range 16). Two static 16-lane lex butterflies.
// rescore: gm = min over 16 keys; thr = gm + DELTA (DELTA >= 2*err + trunc).
//   Dot tile-minima with deq <= thr; rescan a tile (128 codes, 2/lane) iff
//   deq1 + cover*step <= thr (floor-quant both sides => never misses j*).
//   Lex-(value,idx) min of np-exact fp32 FMA-chain dots => np argmin.

typedef float f32x4 __attribute__((ext_vector_type(4)));
typedef short s16x8 __attribute__((ext_vector_type(8)));

#define D_DIM 256
#define N_ROWS 65536
#define K_CODES 2048
#define VQ_EPS 1e-5f
#define DELTA 0.5f
#define COVRANGE 16.0f

__device__ __forceinline__ short bf16s(float f) {
    __hip_bfloat16 h = __float2bfloat16(f);
    return __builtin_bit_cast(short, h);
}
__device__ __forceinline__ unsigned fkey(float f) {       // order-preserving u32
    unsigned u = __float_as_uint(f);
    return (u & 0x80000000u) ? ~u : (u | 0x80000000u);
}
__device__ __forceinline__ float funkey(unsigned k) {
    unsigned u = (k & 0x80000000u) ? (k ^ 0x80000000u) : ~k;
    return __uint_as_float(u);
}
__device__ __forceinline__ void gload16(const void* g, void* l) {
    __builtin_amdgcn_global_load_lds(
        (const __attribute__((address_space(1))) void*)g,
        (__attribute__((address_space(3))) void*)l, 16, 0, 0);
}

// ---------------- prep: embed = embed_sum / clip(usage) -----------------------
__global__ void prep_embed(const float* __restrict__ es, const float* __restrict__ us,
                           float* __restrict__ embed) {
    int i = blockIdx.x * 256 + threadIdx.x;               // 524288
    int k = i >> 8;
    float u = fmaxf(us[k], VQ_EPS);
    embed[i] = es[i] / u;                                 // IEEE div == np bitwise
}

// bf16 convert + swizzle-permute: dst[r][kc][s] = src[r][kc*32 + (s^((r>>1)&3))*8..]
template <int ROWS>
__global__ void prep_swz(const float* __restrict__ src, unsigned short* __restrict__ dst) {
    int gid = blockIdx.x * 256 + threadIdx.x;             // ROWS*32 threads
    int r = gid >> 5, idx = gid & 31;
    int kc = idx >> 2, s = idx & 3;
    int k0 = kc * 32 + (s ^ ((r >> 1) & 3)) * 8;
    const float* p = src + r * D_DIM + k0;
    s16x8 v;
#pragma unroll
    for (int j = 0; j < 8; ++j) v[j] = bf16s(p[j]);
    *(s16x8*)&dst[r * 256 + kc * 32 + s * 8] = v;
}

// numpy pairwise sum of squares over 256 (verified round 4)
__device__ __forceinline__ void np_sumsq_16lane(const float* a, float* out, int g) {
#pragma clang fp contract(off)
    int j = g & 7, h = g >> 3;
    const float* p = a + h * 128;
    float t = p[j];
    float r = t * t;
#pragma unroll
    for (int i = 1; i < 16; ++i) { float v = p[j + 8 * i]; r += v * v; }
    r += __shfl_xor(r, 1);
    r += __shfl_xor(r, 2);
    r += __shfl_xor(r, 4);
    float other = __shfl_xor(r, 8);
    if (g == 0) *out = r + other;
}

__global__ void prep_e2(const float* __restrict__ embed, float* __restrict__ e2) {
    int gid = blockIdx.x * 256 + threadIdx.x;             // 2048 * 16
    int k = gid >> 4;
    np_sumsq_16lane(embed + k * D_DIM, e2 + k, threadIdx.x & 15);
}

__global__ void prep_x2(const float* __restrict__ x, float* __restrict__ x2) {
    int gid = blockIdx.x * 256 + threadIdx.x;             // 65536 * 16
    int r = gid >> 4;
    np_sumsq_16lane(x + r * D_DIM, x2 + r, threadIdx.x & 15);
}

// ---- single bf16 MFMA scan: per-(row,tile) top-2 + cover, no atomics ---------
__launch_bounds__(256, 2)
__global__ void vq_scan(const unsigned short* __restrict__ xswz,
                        const unsigned short* __restrict__ eswz,
                        const float* __restrict__ e2, const float* __restrict__ x2,
                        unsigned* __restrict__ keys, unsigned char* __restrict__ covs) {
    __shared__ __align__(16) short lds[2][2][4096];       // [buf][A/B][8KB]

    const int bid = blockIdx.x;
    const int swz = (bid & 7) * 1024 + (bid >> 3);        // XCD-contiguous tiles
    const int mt = swz >> 4, nt = swz & 15;
    const int m_base = mt * 128, n_base = nt * 128;
    const int tid = threadIdx.x, lane = tid & 63, wid = tid >> 6;
    const int rb = wid * 32;                              // wave: rows rb..rb+31
    const int l15 = lane & 15, lg = lane >> 4;

    f32x4 acc[2][8];
#pragma unroll
    for (int m = 0; m < 2; ++m)
#pragma unroll
        for (int n = 0; n < 8; ++n) { f32x4 z = {0.f, 0.f, 0.f, 0.f}; acc[m][n] = z; }

    auto stage = [&](int buf, int kc) {
#pragma unroll
        for (int i = 0; i < 2; ++i) {
            int off = i * 4096 + wid * 1024 + lane * 16;  // linear LDS dest bytes
            int row = off >> 6, slot = (off >> 4) & 3;    // pre-permuted source
            gload16((const char*)xswz + (((size_t)(m_base + row)) << 9) + (kc << 6) + (slot << 4),
                    (char*)&lds[buf][0][0] + off);
            gload16((const char*)eswz + (((size_t)(n_base + row)) << 9) + (kc << 6) + (slot << 4),
                    (char*)&lds[buf][1][0] + off);
        }
    };
    auto compute = [&](int buf) {
        const short* A = &lds[buf][0][0];
        const short* B = &lds[buf][1][0];
        s16x8 af[2], bf[8];
#pragma unroll
        for (int m = 0; m < 2; ++m) {
            int R = rb + m * 16 + l15, s = lg ^ ((R >> 1) & 3);
            af[m] = *(const s16x8*)&A[R * 32 + s * 8];
        }
#pragma unroll
        for (int n = 0; n < 8; ++n) {
            int R = n * 16 + l15, s = lg ^ ((R >> 1) & 3);
            bf[n] = *(const s16x8*)&B[R * 32 + s * 8];
        }
#pragma unroll
        for (int m = 0; m < 2; ++m)
#pragma unroll
            for (int n = 0; n < 8; ++n)
                acc[m][n] = __builtin_amdgcn_mfma_f32_16x16x32_bf16(af[m], bf[n], acc[m][n], 0, 0, 0);
    };

    stage(0, 0);
    __syncthreads();
#pragma unroll 1
    for (int kc = 0; kc < 8; ++kc) {
        if (kc < 7) stage((kc + 1) & 1, kc + 1);          // loads fly under compute
        compute(kc & 1);
        __syncthreads();                                  // drain gload + readers done
    }

    // epilogue: d2a = (x2 - 2*xe_a) + e2; per (row,tile) top-2 via two static
    // 16-lane lex butterflies (no dynamic register indexing, rule #20).
    // C/D layout (rounds 8/10 verified): col = n*16 + l15, row = lg*4+j (+m*16)
    const int grow0 = m_base + rb + lg * 4;
    float e2v[8];
#pragma unroll
    for (int n = 0; n < 8; ++n) e2v[n] = e2[n_base + n * 16 + l15];

#pragma unroll
    for (int m = 0; m < 2; ++m) {
#pragma unroll
        for (int j = 0; j < 4; ++j) {
            int gr = grow0 + m * 16 + j;
            float x2v = x2[gr];
            float d2v[8];
            float bv1 = __builtin_inff(); int bc1 = 0x7FFFFFFF;
#pragma unroll
            for (int n = 0; n < 8; ++n) {
                d2v[n] = (x2v - 2.0f * acc[m][n][j]) + e2v[n];
                int c = n_base + n * 16 + l15;
                if (d2v[n] < bv1) { bv1 = d2v[n]; bc1 = c; }   // ascending c per lane
            }
#pragma unroll
            for (int s = 1; s < 16; s <<= 1) {            // lex-min butterfly #1
                float ov = __shfl_xor(bv1, s);
                int oc = __shfl_xor(bc1, s);
                if (ov < bv1 || (ov == bv1 && oc < bc1)) { bv1 = ov; bc1 = oc; }
            }
            float bv2 = __builtin_inff(); int bc2 = 0x7FFFFFFF;
#pragma unroll
            for (int n = 0; n < 8; ++n) {                 // exclude winner by code
                int c = n_base + n * 16 + l15;
                if (c != bc1 && d2v[n] < bv2) { bv2 = d2v[n]; bc2 = c; }
            }
#pragma unroll
            for (int s = 1; s < 16; s <<= 1) {            // lex-min butterfly #2
                float ov = __shfl_xor(bv2, s);
                int oc = __shfl_xor(bc2, s);
                if (ov < bv2 || (ov == bv2 && oc < bc2)) { bv2 = ov; bc2 = oc; }
            }
            if (l15 == 0) {
                keys[gr * 16 + nt] = (fkey(bv1) & 0xFFFFF800u) | (unsigned)(bc1 & 0x7FF);
                float q = fminf((bv2 - bv1) * (255.0f / COVRANGE), 255.0f);
                covs[gr * 16 + nt] = (unsigned char)(int)q;   // floor-quant
            }
        }
    }
}

// ------- np-exact rescore (wave per row) + fused gather -----------------------
__launch_bounds__(256, 4)
__global__ void vq_rescore(const float* __restrict__ x, const float* __restrict__ embed,
                           const float* __restrict__ e2, const float* __restrict__ x2,
                           const unsigned* __restrict__ keys,
                           const unsigned char* __restrict__ covs,
                           const float* __restrict__ es, const float* __restrict__ us,
                           float* __restrict__ out) {
    const int tid = threadIdx.x, w = tid >> 6, lane = tid & 63;
    const int r = blockIdx.x * 4 + w;
    const int t16 = lane & 15;
    const float x2v = x2[r];

    unsigned key = keys[r * 16 + t16];
    unsigned kd = key & 0xFFFFF800u;                      // truncated value key
    unsigned kmin = kd;
#pragma unroll
    for (int s = 1; s < 16; s <<= 1) {                    // gm over 16 tiles
        unsigned ok = __shfl_xor(kmin, s);
        kmin = ok < kmin ? ok : kmin;
    }
    const float thr = funkey(kmin) + DELTA;
    const float deq = funkey(kd);                         // floor of tile min1

    bool cand = (lane < 16) && (deq <= thr);
    bool resc = (lane < 16) &&
                (deq + (float)covs[r * 16 + t16] * (COVRANGE / 255.0f) <= thr);
    unsigned long long rmask = __ballot(resc);            // bits 0..15 = tiles

    float bv = __builtin_inff();
    int bi = 0x7FFFFFFF;

    auto dot_d2 = [&](int code) -> float {
        float t = 0.0f;
#pragma unroll 8
        for (int k4 = 0; k4 < 64; ++k4) {                 // single chain, k ascending
            f32x4 a4 = *(const f32x4*)&x[r * D_DIM + k4 * 4];   // wave-uniform
            f32x4 e4 = *(const f32x4*)&embed[code * D_DIM + k4 * 4];
            t = __builtin_fmaf(a4[0], e4[0], t);
            t = __builtin_fmaf(a4[1], e4[1], t);
            t = __builtin_fmaf(a4[2], e4[2], t);
            t = __builtin_fmaf(a4[3], e4[3], t);
        }
        return (x2v - 2.0f * t) + e2[code];               // np op order
    };
    auto lexmin = [&](float d2, int code) {
        if (d2 < bv || (d2 == bv && code < bi)) { bv = d2; bi = code; }
    };

    if (cand) {                                           // tile-top-1 candidates
        int code = (int)(key & 0x7FFu);
        lexmin(dot_d2(code), code);
    }
    while (rmask) {                                       // tiles needing rescan
        int t = __ffsll(rmask) - 1;
        rmask &= rmask - 1;
        lexmin(dot_d2(t * 128 + lane), t * 128 + lane);
        lexmin(dot_d2(t * 128 + 64 + lane), t * 128 + 64 + lane);
    }
#pragma unroll
    for (int s = 1; s < 64; s <<= 1) {                    // 64-lane lex allreduce
        float ov = __shfl_xor(bv, s);
        int oi = __shfl_xor(bi, s);
        if (ov < bv || (ov == bv && oi < bi)) { bv = ov; bi = oi; }
    }
    if (lane == 0) out[r] = (float)bi;

    // fused gather: quantized[r] = es[bi]/max(us[bi],eps); 64 lanes x 4 floats
    float u = fmaxf(us[bi], VQ_EPS);
    f32x4 wv = *(const f32x4*)&es[bi * D_DIM + lane * 4];
    f32x4 o;
#pragma unroll
    for (int j = 0; j < 4; ++j) o[j] = wv[j] / u;         // IEEE div == np bitwise
    *(f32x4*)&out[N_ROWS + r * D_DIM + lane * 4] = o;
}

extern "C" void kernel_launch(void* const* d_in, const int* in_sizes, int n_in,
                              void* d_out, int out_size, void* d_ws, size_t ws_size,
                              hipStream_t stream) {
    const float* x = (const float*)d_in[0];               // [65536, 256]
    const float* es = (const float*)d_in[1];              // [2048, 256]
    const float* us = (const float*)d_in[2];              // [2048]
    float* out = (float*)d_out;

    char* w = (char*)d_ws;                                // total 42,213,376 B
    unsigned short* xswz = (unsigned short*)(w);                  // 33,554,432
    unsigned short* eswz = (unsigned short*)(w + 33554432);       //  1,048,576
    float* embed         = (float*)(w + 34603008);                //  2,097,152
    float* e2            = (float*)(w + 36700160);                //      8,192
    float* x2            = (float*)(w + 36708352);                //    262,144
    unsigned* keys       = (unsigned*)(w + 36970496);             //  4,194,304
    unsigned char* covs  = (unsigned char*)(w + 41164800);        //  1,048,576

    hipLaunchKernelGGL(prep_embed, dim3(2048), dim3(256), 0, stream, es, us, embed);
    hipLaunchKernelGGL((prep_swz<K_CODES>), dim3(256), dim3(256), 0, stream, embed, eswz);
    hipLaunchKernelGGL(prep_e2, dim3(128), dim3(256), 0, stream, embed, e2);
    hipLaunchKernelGGL(prep_x2, dim3(4096), dim3(256), 0, stream, x, x2);
    hipLaunchKernelGGL((prep_swz<N_ROWS>), dim3(8192), dim3(256), 0, stream, x, xswz);
    hipLaunchKernelGGL(vq_scan, dim3(8192), dim3(256), 0, stream,
                       xswz, eswz, e2, x2, keys, covs);
    hipLaunchKernelGGL(vq_rescore, dim3(16384), dim3(256), 0, stream,
                       x, embed, e2, x2, keys, covs, es, us, out);
}

// Round 13
// 280.131 us; speedup vs baseline: 1.8596x; 1.6428x over previous
//
#include <hip/hip_runtime.h>
#include <hip/hip_bf16.h>

// MimiEuclideanCodebook — SINGLE bf16-MFMA scan (gload_lds staging) with
// top-2+cover epilogue (no atomics, deterministic) + LDS-staged np-bit-exact
// rescore + fused gather.
// scan: per (row, 128-col tile) store key = trunc20(fkey(min1 d2a)) | code and
//   cover = floorq(min2 - min1, range 16). Two static 16-lane lex butterflies.
// rescore: gm = min over 16 keys; thr = gm + DELTA (>= 2*err + trunc slack).
//   Candidate codes' embed rows staged 4-at-a-time into LDS (coalesced), then
//   np-exact fp32 FMA chains run from LDS (dep chain is the floor, not L2
//   latency). Tile rescan iff lowerbound(min2) <= thr (x from LDS).
//   Lex-(value,idx) min => np argmin; first-min ties.

typedef float f32x4 __attribute__((ext_vector_type(4)));
typedef short s16x8 __attribute__((ext_vector_type(8)));

#define D_DIM 256
#define N_ROWS 65536
#define K_CODES 2048
#define VQ_EPS 1e-5f
#define DELTA 0.5f
#define COVRANGE 16.0f

__device__ __forceinline__ short bf16s(float f) {
    __hip_bfloat16 h = __float2bfloat16(f);
    return __builtin_bit_cast(short, h);
}
__device__ __forceinline__ unsigned fkey(float f) {       // order-preserving u32
    unsigned u = __float_as_uint(f);
    return (u & 0x80000000u) ? ~u : (u | 0x80000000u);
}
__device__ __forceinline__ float funkey(unsigned k) {
    unsigned u = (k & 0x80000000u) ? (k ^ 0x80000000u) : ~k;
    return __uint_as_float(u);
}
__device__ __forceinline__ void gload16(const void* g, void* l) {
    __builtin_amdgcn_global_load_lds(
        (const __attribute__((address_space(1))) void*)g,
        (__attribute__((address_space(3))) void*)l, 16, 0, 0);
}

// ---------------- prep: embed = embed_sum / clip(usage) -----------------------
__global__ void prep_embed(const float* __restrict__ es, const float* __restrict__ us,
                           float* __restrict__ embed) {
    int i = blockIdx.x * 256 + threadIdx.x;               // 524288
    int k = i >> 8;
    float u = fmaxf(us[k], VQ_EPS);
    embed[i] = es[i] / u;                                 // IEEE div == np bitwise
}

// bf16 convert + swizzle-permute: dst[r][kc][s] = src[r][kc*32 + (s^((r>>1)&3))*8..]
template <int ROWS>
__global__ void prep_swz(const float* __restrict__ src, unsigned short* __restrict__ dst) {
    int gid = blockIdx.x * 256 + threadIdx.x;             // ROWS*32 threads
    int r = gid >> 5, idx = gid & 31;
    int kc = idx >> 2, s = idx & 3;
    int k0 = kc * 32 + (s ^ ((r >> 1) & 3)) * 8;
    const float* p = src + r * D_DIM + k0;
    s16x8 v;
#pragma unroll
    for (int j = 0; j < 8; ++j) v[j] = bf16s(p[j]);
    *(s16x8*)&dst[r * 256 + kc * 32 + s * 8] = v;
}

// numpy pairwise sum of squares over 256 (verified round 4)
__device__ __forceinline__ void np_sumsq_16lane(const float* a, float* out, int g) {
#pragma clang fp contract(off)
    int j = g & 7, h = g >> 3;
    const float* p = a + h * 128;
    float t = p[j];
    float r = t * t;
#pragma unroll
    for (int i = 1; i < 16; ++i) { float v = p[j + 8 * i]; r += v * v; }
    r += __shfl_xor(r, 1);
    r += __shfl_xor(r, 2);
    r += __shfl_xor(r, 4);
    float other = __shfl_xor(r, 8);
    if (g == 0) *out = r + other;
}

__global__ void prep_e2(const float* __restrict__ embed, float* __restrict__ e2) {
    int gid = blockIdx.x * 256 + threadIdx.x;             // 2048 * 16
    int k = gid >> 4;
    np_sumsq_16lane(embed + k * D_DIM, e2 + k, threadIdx.x & 15);
}

__global__ void prep_x2(const float* __restrict__ x, float* __restrict__ x2) {
    int gid = blockIdx.x * 256 + threadIdx.x;             // 65536 * 16
    int r = gid >> 4;
    np_sumsq_16lane(x + r * D_DIM, x2 + r, threadIdx.x & 15);
}

// ---- single bf16 MFMA scan: per-(row,tile) top-2 + cover, no atomics ---------
__launch_bounds__(256, 2)
__global__ void vq_scan(const unsigned short* __restrict__ xswz,
                        const unsigned short* __restrict__ eswz,
                        const float* __restrict__ e2, const float* __restrict__ x2,
                        unsigned* __restrict__ keys, unsigned char* __restrict__ covs) {
    __shared__ __align__(16) short lds[2][2][4096];       // [buf][A/B][8KB]

    const int bid = blockIdx.x;
    const int swz = (bid & 7) * 1024 + (bid >> 3);        // XCD-contiguous tiles
    const int mt = swz >> 4, nt = swz & 15;
    const int m_base = mt * 128, n_base = nt * 128;
    const int tid = threadIdx.x, lane = tid & 63, wid = tid >> 6;
    const int rb = wid * 32;                              // wave: rows rb..rb+31
    const int l15 = lane & 15, lg = lane >> 4;

    f32x4 acc[2][8];
#pragma unroll
    for (int m = 0; m < 2; ++m)
#pragma unroll
        for (int n = 0; n < 8; ++n) { f32x4 z = {0.f, 0.f, 0.f, 0.f}; acc[m][n] = z; }

    auto stage = [&](int buf, int kc) {
#pragma unroll
        for (int i = 0; i < 2; ++i) {
            int off = i * 4096 + wid * 1024 + lane * 16;  // linear LDS dest bytes
            int row = off >> 6, slot = (off >> 4) & 3;    // pre-permuted source
            gload16((const char*)xswz + (((size_t)(m_base + row)) << 9) + (kc << 6) + (slot << 4),
                    (char*)&lds[buf][0][0] + off);
            gload16((const char*)eswz + (((size_t)(n_base + row)) << 9) + (kc << 6) + (slot << 4),
                    (char*)&lds[buf][1][0] + off);
        }
    };
    auto compute = [&](int buf) {
        const short* A = &lds[buf][0][0];
        const short* B = &lds[buf][1][0];
        s16x8 af[2], bf[8];
#pragma unroll
        for (int m = 0; m < 2; ++m) {
            int R = rb + m * 16 + l15, s = lg ^ ((R >> 1) & 3);
            af[m] = *(const s16x8*)&A[R * 32 + s * 8];
        }
#pragma unroll
        for (int n = 0; n < 8; ++n) {
            int R = n * 16 + l15, s = lg ^ ((R >> 1) & 3);
            bf[n] = *(const s16x8*)&B[R * 32 + s * 8];
        }
#pragma unroll
        for (int m = 0; m < 2; ++m)
#pragma unroll
            for (int n = 0; n < 8; ++n)
                acc[m][n] = __builtin_amdgcn_mfma_f32_16x16x32_bf16(af[m], bf[n], acc[m][n], 0, 0, 0);
    };

    stage(0, 0);
    __syncthreads();
#pragma unroll 1
    for (int kc = 0; kc < 8; ++kc) {
        if (kc < 7) stage((kc + 1) & 1, kc + 1);          // loads fly under compute
        compute(kc & 1);
        __syncthreads();                                  // drain gload + readers done
    }

    // epilogue: d2a = (x2 - 2*xe_a) + e2; per (row,tile) top-2 via two static
    // 16-lane lex butterflies (no dynamic register indexing, rule #20).
    // C/D layout (rounds 8/10 verified): col = n*16 + l15, row = lg*4+j (+m*16)
    const int grow0 = m_base + rb + lg * 4;
    float e2v[8];
#pragma unroll
    for (int n = 0; n < 8; ++n) e2v[n] = e2[n_base + n * 16 + l15];

#pragma unroll
    for (int m = 0; m < 2; ++m) {
#pragma unroll
        for (int j = 0; j < 4; ++j) {
            int gr = grow0 + m * 16 + j;
            float x2v = x2[gr];
            float d2v[8];
            float bv1 = __builtin_inff(); int bc1 = 0x7FFFFFFF;
#pragma unroll
            for (int n = 0; n < 8; ++n) {
                d2v[n] = (x2v - 2.0f * acc[m][n][j]) + e2v[n];
                int c = n_base + n * 16 + l15;
                if (d2v[n] < bv1) { bv1 = d2v[n]; bc1 = c; }   // ascending c per lane
            }
#pragma unroll
            for (int s = 1; s < 16; s <<= 1) {            // lex-min butterfly #1
                float ov = __shfl_xor(bv1, s);
                int oc = __shfl_xor(bc1, s);
                if (ov < bv1 || (ov == bv1 && oc < bc1)) { bv1 = ov; bc1 = oc; }
            }
            float bv2 = __builtin_inff(); int bc2 = 0x7FFFFFFF;
#pragma unroll
            for (int n = 0; n < 8; ++n) {                 // exclude winner by code
                int c = n_base + n * 16 + l15;
                if (c != bc1 && d2v[n] < bv2) { bv2 = d2v[n]; bc2 = c; }
            }
#pragma unroll
            for (int s = 1; s < 16; s <<= 1) {            // lex-min butterfly #2
                float ov = __shfl_xor(bv2, s);
                int oc = __shfl_xor(bc2, s);
                if (ov < bv2 || (ov == bv2 && oc < bc2)) { bv2 = ov; bc2 = oc; }
            }
            if (l15 == 0) {
                keys[gr * 16 + nt] = (fkey(bv1) & 0xFFFFF800u) | (unsigned)(bc1 & 0x7FF);
                float q = fminf((bv2 - bv1) * (255.0f / COVRANGE), 255.0f);
                covs[gr * 16 + nt] = (unsigned char)(int)q;   // floor-quant
            }
        }
    }
}

// ------- LDS-staged np-exact rescore (wave per row) + fused gather ------------
__launch_bounds__(256, 4)
__global__ void vq_rescore(const float* __restrict__ x, const float* __restrict__ embed,
                           const float* __restrict__ e2, const float* __restrict__ x2,
                           const unsigned* __restrict__ keys,
                           const unsigned char* __restrict__ covs,
                           const float* __restrict__ es, const float* __restrict__ us,
                           float* __restrict__ out) {
    __shared__ float lx[4][256];                          // x rows (exact fp32)
    __shared__ float le[4][4][260];                       // 4 staged embed rows/wave
    __shared__ int lcode[4][16];
    __shared__ int lnc[4];

    const int tid = threadIdx.x, w = tid >> 6, lane = tid & 63;
    const int r = blockIdx.x * 4 + w;
    const int t16 = lane & 15;
    const float x2v = x2[r];

    // stage x row (coalesced 1KB; LDS round-trip is bit-exact)
    *(f32x4*)&lx[w][lane * 4] = *(const f32x4*)&x[r * D_DIM + lane * 4];

    unsigned key = keys[r * 16 + t16];
    unsigned kd = key & 0xFFFFF800u;                      // truncated value key
    unsigned kmin = kd;
#pragma unroll
    for (int s = 1; s < 16; s <<= 1) {                    // gm over 16 tiles
        unsigned ok = __shfl_xor(kmin, s);
        kmin = ok < kmin ? ok : kmin;
    }
    const float thr = funkey(kmin) + DELTA;
    const float deq = funkey(kd);                         // floor of tile min1

    bool cand = (lane < 16) && (deq <= thr);
    bool resc = (lane < 16) &&
                (deq + (float)covs[r * 16 + t16] * (COVRANGE / 255.0f) <= thr);
    unsigned long long cmask = __ballot(cand);
    unsigned long long rmask = __ballot(resc);            // bits 0..15 = tiles
    if (cand)
        lcode[w][__popcll(cmask & ((1ull << lane) - 1ull))] = (int)(key & 0x7FFu);
    if (lane == 0) lnc[w] = __popcll(cmask);
    __syncthreads();                                      // lx, lcode, lnc visible

    int gmax = lnc[0];
#pragma unroll
    for (int i = 1; i < 4; ++i) gmax = max(gmax, lnc[i]);
    gmax = (gmax + 3) >> 2;                               // block-uniform groups

    float bv = __builtin_inff();
    int bi = 0x7FFFFFFF;
    auto lexmin = [&](float d2, int code) {
        if (d2 < bv || (d2 == bv && code < bi)) { bv = d2; bi = code; }
    };

#pragma unroll 1
    for (int g = 0; g < gmax; ++g) {
        const int nc = lnc[w];                            // wave-uniform
#pragma unroll
        for (int v = 0; v < 4; ++v) {                     // stage <=4 embed rows
            int idx = g * 4 + v;
            if (idx < nc) {
                int code = lcode[w][idx];
                *(f32x4*)&le[w][v][lane * 4] =
                    *(const f32x4*)&embed[code * D_DIM + lane * 4];
            }
        }
        __syncthreads();
        int idx = g * 4 + lane;                           // lanes 0..3 run chains
        if (lane < 4 && idx < nc) {
            int code = lcode[w][idx];
            float t = 0.0f;
#pragma unroll 8
            for (int k4 = 0; k4 < 64; ++k4) {             // single chain, k ascending
                f32x4 a4 = *(const f32x4*)&lx[w][k4 * 4];     // broadcast
                f32x4 e4 = *(const f32x4*)&le[w][lane][k4 * 4];
                t = __builtin_fmaf(a4[0], e4[0], t);
                t = __builtin_fmaf(a4[1], e4[1], t);
                t = __builtin_fmaf(a4[2], e4[2], t);
                t = __builtin_fmaf(a4[3], e4[3], t);
            }
            lexmin((x2v - 2.0f * t) + e2[code], code);    // np op order
        }
        __syncthreads();                                  // before le overwrite
    }

    // rare: tiles whose min2 lower-bound clears thr -> exact rescan (128 codes,
    // 2 per lane; x from LDS, embed streamed from global)
    while (rmask) {
        int t2 = __ffsll(rmask) - 1;
        rmask &= rmask - 1;
#pragma unroll
        for (int q = 0; q < 2; ++q) {
            int code = t2 * 128 + q * 64 + lane;
            float t = 0.0f;
#pragma unroll 8
            for (int k4 = 0; k4 < 64; ++k4) {
                f32x4 a4 = *(const f32x4*)&lx[w][k4 * 4];
                f32x4 e4 = *(const f32x4*)&embed[code * D_DIM + k4 * 4];
                t = __builtin_fmaf(a4[0], e4[0], t);
                t = __builtin_fmaf(a4[1], e4[1], t);
                t = __builtin_fmaf(a4[2], e4[2], t);
                t = __builtin_fmaf(a4[3], e4[3], t);
            }
            lexmin((x2v - 2.0f * t) + e2[code], code);
        }
    }

#pragma unroll
    for (int s = 1; s < 64; s <<= 1) {                    // 64-lane lex allreduce
        float ov = __shfl_xor(bv, s);
        int oi = __shfl_xor(bi, s);
        if (ov < bv || (ov == bv && oi < bi)) { bv = ov; bi = oi; }
    }
    if (lane == 0) out[r] = (float)bi;

    // fused gather: quantized[r] = es[bi]/max(us[bi],eps); 64 lanes x 4 floats
    float u = fmaxf(us[bi], VQ_EPS);
    f32x4 wv = *(const f32x4*)&es[bi * D_DIM + lane * 4];
    f32x4 o;
#pragma unroll
    for (int j = 0; j < 4; ++j) o[j] = wv[j] / u;         // IEEE div == np bitwise
    *(f32x4*)&out[N_ROWS + r * D_DIM + lane * 4] = o;
}

extern "C" void kernel_launch(void* const* d_in, const int* in_sizes, int n_in,
                              void* d_out, int out_size, void* d_ws, size_t ws_size,
                              hipStream_t stream) {
    const float* x = (const float*)d_in[0];               // [65536, 256]
    const float* es = (const float*)d_in[1];              // [2048, 256]
    const float* us = (const float*)d_in[2];              // [2048]
    float* out = (float*)d_out;

    char* w = (char*)d_ws;                                // total 42,213,376 B
    unsigned short* xswz = (unsigned short*)(w);                  // 33,554,432
    unsigned short* eswz = (unsigned short*)(w + 33554432);       //  1,048,576
    float* embed         = (float*)(w + 34603008);                //  2,097,152
    float* e2            = (float*)(w + 36700160);                //      8,192
    float* x2            = (float*)(w + 36708352);                //    262,144
    unsigned* keys       = (unsigned*)(w + 36970496);             //  4,194,304
    unsigned char* covs  = (unsigned char*)(w + 41164800);        //  1,048,576

    hipLaunchKernelGGL(prep_embed, dim3(2048), dim3(256), 0, stream, es, us, embed);
    hipLaunchKernelGGL((prep_swz<K_CODES>), dim3(256), dim3(256), 0, stream, embed, eswz);
    hipLaunchKernelGGL(prep_e2, dim3(128), dim3(256), 0, stream, embed, e2);
    hipLaunchKernelGGL(prep_x2, dim3(4096), dim3(256), 0, stream, x, x2);
    hipLaunchKernelGGL((prep_swz<N_ROWS>), dim3(8192), dim3(256), 0, stream, x, xswz);
    hipLaunchKernelGGL(vq_scan, dim3(8192), dim3(256), 0, stream,
                       xswz, eswz, e2, x2, keys, covs);
    hipLaunchKernelGGL(vq_rescore, dim3(16384), dim3(256), 0, stream,
                       x, embed, e2, x2, keys, covs, es, us, out);
}

// Round 14
// 238.785 us; speedup vs baseline: 2.1816x; 1.1732x over previous
//
#include <hip/hip_runtime.h>
#include <hip/hip_bf16.h>

// MimiEuclideanCodebook — SINGLE bf16-MFMA scan (gload_lds staging) with
// packed-u32 top-2 epilogue (one butterfly, no atomics, deterministic) +
// LDS-staged np-bit-exact rescore + fused gather.
// scan: per (row, 128-col tile) store k1,k2 = two smallest packed keys
//   ((fkey(d2a) & ~0x7FF) | code) — u32 min == lex-(value,code) min.
// rescore: gm = min over 16 k1-truncs; thr = gm + DELTA (>= 2*err + trunc).
//   Candidates: tile-top-1 codes with deq1 <= thr (embed rows staged in LDS,
//   np-exact fp32 FMA chains from LDS). Tile rescan iff deq2 <= thr (min2
//   floor-dequant is a valid lower bound). Lex-(value,idx) min => np argmin.

typedef float f32x4 __attribute__((ext_vector_type(4)));
typedef short s16x8 __attribute__((ext_vector_type(8)));

#define D_DIM 256
#define N_ROWS 65536
#define K_CODES 2048
#define VQ_EPS 1e-5f
#define DELTA 0.5f

__device__ __forceinline__ short bf16s(float f) {
    __hip_bfloat16 h = __float2bfloat16(f);
    return __builtin_bit_cast(short, h);
}
__device__ __forceinline__ unsigned fkey(float f) {       // order-preserving u32
    unsigned u = __float_as_uint(f);
    return u ^ (unsigned)(((int)u >> 31) | (int)0x80000000);
}
__device__ __forceinline__ float funkey(unsigned k) {
    unsigned u = (k & 0x80000000u) ? (k ^ 0x80000000u) : ~k;
    return __uint_as_float(u);
}
__device__ __forceinline__ void gload16(const void* g, void* l) {
    __builtin_amdgcn_global_load_lds(
        (const __attribute__((address_space(1))) void*)g,
        (__attribute__((address_space(3))) void*)l, 16, 0, 0);
}

// ---------------- prep: embed = embed_sum / clip(usage) -----------------------
__global__ void prep_embed(const float* __restrict__ es, const float* __restrict__ us,
                           float* __restrict__ embed) {
    int i = blockIdx.x * 256 + threadIdx.x;               // 524288
    int k = i >> 8;
    float u = fmaxf(us[k], VQ_EPS);
    embed[i] = es[i] / u;                                 // IEEE div == np bitwise
}

// numpy pairwise sum of squares over 256 (verified round 4)
__device__ __forceinline__ void np_sumsq_16lane(const float* a, float* out, int g) {
#pragma clang fp contract(off)
    int j = g & 7, h = g >> 3;
    const float* p = a + h * 128;
    float t = p[j];
    float r = t * t;
#pragma unroll
    for (int i = 1; i < 16; ++i) { float v = p[j + 8 * i]; r += v * v; }
    r += __shfl_xor(r, 1);
    r += __shfl_xor(r, 2);
    r += __shfl_xor(r, 4);
    float other = __shfl_xor(r, 8);
    if (g == 0) *out = r + other;
}

// bf16 convert + swizzle-permute for embed (2048 rows)
__global__ void prep_swz_e(const float* __restrict__ src, unsigned short* __restrict__ dst) {
    int gid = blockIdx.x * 256 + threadIdx.x;             // 2048*32
    int r = gid >> 5, idx = gid & 31;
    int kc = idx >> 2, s = idx & 3;
    int k0 = kc * 32 + (s ^ ((r >> 1) & 3)) * 8;
    const float* p = src + r * D_DIM + k0;
    s16x8 v;
#pragma unroll
    for (int j = 0; j < 8; ++j) v[j] = bf16s(p[j]);
    *(s16x8*)&dst[r * 256 + kc * 32 + s * 8] = v;
}

__global__ void prep_e2(const float* __restrict__ embed, float* __restrict__ e2) {
    int gid = blockIdx.x * 256 + threadIdx.x;             // 2048 * 16
    int k = gid >> 4;
    np_sumsq_16lane(embed + k * D_DIM, e2 + k, threadIdx.x & 15);
}

// FUSED: x bf16-swizzle + np-pairwise x2 (one HBM pass over x)
__global__ void prep_x(const float* __restrict__ x, unsigned short* __restrict__ dst,
                       float* __restrict__ x2) {
    int gid = blockIdx.x * 256 + threadIdx.x;             // 65536*32
    int r = gid >> 5, idx = gid & 31;
    int kc = idx >> 2, s = idx & 3;
    int k0 = kc * 32 + (s ^ ((r >> 1) & 3)) * 8;
    const float* p = x + r * D_DIM + k0;
    s16x8 v;
#pragma unroll
    for (int j = 0; j < 8; ++j) v[j] = bf16s(p[j]);
    *(s16x8*)&dst[r * 256 + kc * 32 + s * 8] = v;
    if (idx < 16)                                         // L1-hot re-read
        np_sumsq_16lane(x + r * D_DIM, x2 + r, idx);
}

// ---- single bf16 MFMA scan: per-(row,tile) packed top-2, no atomics ----------
__launch_bounds__(256, 2)
__global__ void vq_scan(const unsigned short* __restrict__ xswz,
                        const unsigned short* __restrict__ eswz,
                        const float* __restrict__ e2, const float* __restrict__ x2,
                        unsigned* __restrict__ keys1, unsigned* __restrict__ keys2) {
    __shared__ __align__(16) short lds[2][2][4096];       // [buf][A/B][8KB]

    const int bid = blockIdx.x;
    const int swz = (bid & 7) * 1024 + (bid >> 3);        // XCD-contiguous tiles
    const int mt = swz >> 4, nt = swz & 15;
    const int m_base = mt * 128, n_base = nt * 128;
    const int tid = threadIdx.x, lane = tid & 63, wid = tid >> 6;
    const int rb = wid * 32;                              // wave: rows rb..rb+31
    const int l15 = lane & 15, lg = lane >> 4;

    f32x4 acc[2][8];
#pragma unroll
    for (int m = 0; m < 2; ++m)
#pragma unroll
        for (int n = 0; n < 8; ++n) { f32x4 z = {0.f, 0.f, 0.f, 0.f}; acc[m][n] = z; }

    auto stage = [&](int buf, int kc) {
#pragma unroll
        for (int i = 0; i < 2; ++i) {
            int off = i * 4096 + wid * 1024 + lane * 16;  // linear LDS dest bytes
            int row = off >> 6, slot = (off >> 4) & 3;    // pre-permuted source
            gload16((const char*)xswz + (((size_t)(m_base + row)) << 9) + (kc << 6) + (slot << 4),
                    (char*)&lds[buf][0][0] + off);
            gload16((const char*)eswz + (((size_t)(n_base + row)) << 9) + (kc << 6) + (slot << 4),
                    (char*)&lds[buf][1][0] + off);
        }
    };
    auto compute = [&](int buf) {
        const short* A = &lds[buf][0][0];
        const short* B = &lds[buf][1][0];
        s16x8 af[2], bf[8];
#pragma unroll
        for (int m = 0; m < 2; ++m) {
            int R = rb + m * 16 + l15, s = lg ^ ((R >> 1) & 3);
            af[m] = *(const s16x8*)&A[R * 32 + s * 8];
        }
#pragma unroll
        for (int n = 0; n < 8; ++n) {
            int R = n * 16 + l15, s = lg ^ ((R >> 1) & 3);
            bf[n] = *(const s16x8*)&B[R * 32 + s * 8];
        }
#pragma unroll
        for (int m = 0; m < 2; ++m)
#pragma unroll
            for (int n = 0; n < 8; ++n)
                acc[m][n] = __builtin_amdgcn_mfma_f32_16x16x32_bf16(af[m], bf[n], acc[m][n], 0, 0, 0);
    };

    stage(0, 0);
    __syncthreads();
#pragma unroll 1
    for (int kc = 0; kc < 8; ++kc) {
        if (kc < 7) stage((kc + 1) & 1, kc + 1);          // loads fly under compute
        compute(kc & 1);
        __syncthreads();                                  // drain gload + readers done
    }

    // epilogue: pack d2a into lex keys; per-lane top-2 (3 min/max per value);
    // ONE 4-step pair-merge butterfly over 16 lanes. No dynamic reg indexing.
    // C/D layout (rounds 8/10 verified): col = n*16 + l15, row = lg*4+j (+m*16)
    const int grow0 = m_base + rb + lg * 4;
    float e2v[8];
#pragma unroll
    for (int n = 0; n < 8; ++n) e2v[n] = e2[n_base + n * 16 + l15];

#pragma unroll
    for (int m = 0; m < 2; ++m) {
#pragma unroll
        for (int j = 0; j < 4; ++j) {
            int gr = grow0 + m * 16 + j;
            float x2v = x2[gr];
            unsigned k1 = 0xFFFFFFFFu, k2 = 0xFFFFFFFFu;
#pragma unroll
            for (int n = 0; n < 8; ++n) {
                float d2 = (x2v - 2.0f * acc[m][n][j]) + e2v[n];
                unsigned pk = (fkey(d2) & 0xFFFFF800u)
                              | (unsigned)(n_base + n * 16 + l15);
                unsigned lo = pk < k1 ? pk : k1;
                unsigned hi = pk < k1 ? k1 : pk;
                k2 = hi < k2 ? hi : k2;
                k1 = lo;
            }
#pragma unroll
            for (int s = 1; s < 16; s <<= 1) {            // bitonic pair-merge
                unsigned o1 = __shfl_xor(k1, s);
                unsigned o2 = __shfl_xor(k2, s);
                unsigned lo = o1 < k1 ? o1 : k1;
                unsigned hi = o1 < k1 ? k1 : o1;
                unsigned m2 = o2 < k2 ? o2 : k2;
                k2 = hi < m2 ? hi : m2;
                k1 = lo;
            }
            if (l15 == 0) {
                keys1[gr * 16 + nt] = k1;
                keys2[gr * 16 + nt] = k2;
            }
        }
    }
}

// ------- LDS-staged np-exact rescore (wave per row) + fused gather ------------
__launch_bounds__(256, 4)
__global__ void vq_rescore(const float* __restrict__ x, const float* __restrict__ embed,
                           const float* __restrict__ e2, const float* __restrict__ x2,
                           const unsigned* __restrict__ keys1,
                           const unsigned* __restrict__ keys2,
                           const float* __restrict__ es, const float* __restrict__ us,
                           float* __restrict__ out) {
    __shared__ float lx[4][256];                          // x rows (exact fp32)
    __shared__ float le[4][4][260];                       // 4 staged embed rows/wave
    __shared__ int lcode[4][16];
    __shared__ int lnc[4];

    const int tid = threadIdx.x, w = tid >> 6, lane = tid & 63;
    const int r = blockIdx.x * 4 + w;
    const int t16 = lane & 15;
    const float x2v = x2[r];

    // stage x row (coalesced 1KB; LDS round-trip is bit-exact)
    *(f32x4*)&lx[w][lane * 4] = *(const f32x4*)&x[r * D_DIM + lane * 4];

    unsigned key = keys1[r * 16 + t16];
    unsigned kd = key & 0xFFFFF800u;                      // truncated value key
    unsigned kmin = kd;
#pragma unroll
    for (int s = 1; s < 16; s <<= 1) {                    // gm over 16 tiles
        unsigned ok = __shfl_xor(kmin, s);
        kmin = ok < kmin ? ok : kmin;
    }
    const float thr = funkey(kmin) + DELTA;
    const float deq = funkey(kd);                         // floor of tile min1

    bool cand = (lane < 16) && (deq <= thr);
    bool resc = (lane < 16) &&
                (funkey(keys2[r * 16 + t16] & 0xFFFFF800u) <= thr);
    unsigned long long cmask = __ballot(cand);
    unsigned long long rmask = __ballot(resc);            // bits 0..15 = tiles
    if (cand)
        lcode[w][__popcll(cmask & ((1ull << lane) - 1ull))] = (int)(key & 0x7FFu);
    if (lane == 0) lnc[w] = __popcll(cmask);
    __syncthreads();                                      // lx, lcode, lnc visible

    int gmax = lnc[0];
#pragma unroll
    for (int i = 1; i < 4; ++i) gmax = max(gmax, lnc[i]);
    gmax = (gmax + 3) >> 2;                               // block-uniform groups

    float bv = __builtin_inff();
    int bi = 0x7FFFFFFF;
    auto lexmin = [&](float d2, int code) {
        if (d2 < bv || (d2 == bv && code < bi)) { bv = d2; bi = code; }
    };

#pragma unroll 1
    for (int g = 0; g < gmax; ++g) {
        const int nc = lnc[w];                            // wave-uniform
#pragma unroll
        for (int v = 0; v < 4; ++v) {                     // stage <=4 embed rows
            int idx = g * 4 + v;
            if (idx < nc) {
                int code = lcode[w][idx];
                *(f32x4*)&le[w][v][lane * 4] =
                    *(const f32x4*)&embed[code * D_DIM + lane * 4];
            }
        }
        __syncthreads();
        int idx = g * 4 + lane;                           // lanes 0..3 run chains
        if (lane < 4 && idx < nc) {
            int code = lcode[w][idx];
            float t = 0.0f;
#pragma unroll 8
            for (int k4 = 0; k4 < 64; ++k4) {             // single chain, k ascending
                f32x4 a4 = *(const f32x4*)&lx[w][k4 * 4];     // broadcast
                f32x4 e4 = *(const f32x4*)&le[w][lane][k4 * 4];
                t = __builtin_fmaf(a4[0], e4[0], t);
                t = __builtin_fmaf(a4[1], e4[1], t);
                t = __builtin_fmaf(a4[2], e4[2], t);
                t = __builtin_fmaf(a4[3], e4[3], t);
            }
            lexmin((x2v - 2.0f * t) + e2[code], code);    // np op order
        }
        __syncthreads();                                  // before le overwrite
    }

    // rare: tiles whose min2 lower-bound clears thr -> exact rescan (128 codes,
    // 2 per lane; x from LDS, embed streamed from global)
    while (rmask) {
        int t2 = __ffsll(rmask) - 1;
        rmask &= rmask - 1;
#pragma unroll
        for (int q = 0; q < 2; ++q) {
            int code = t2 * 128 + q * 64 + lane;
            float t = 0.0f;
#pragma unroll 8
            for (int k4 = 0; k4 < 64; ++k4) {
                f32x4 a4 = *(const f32x4*)&lx[w][k4 * 4];
                f32x4 e4 = *(const f32x4*)&embed[code * D_DIM + k4 * 4];
                t = __builtin_fmaf(a4[0], e4[0], t);
                t = __builtin_fmaf(a4[1], e4[1], t);
                t = __builtin_fmaf(a4[2], e4[2], t);
                t = __builtin_fmaf(a4[3], e4[3], t);
            }
            lexmin((x2v - 2.0f * t) + e2[code], code);
        }
    }

#pragma unroll
    for (int s = 1; s < 64; s <<= 1) {                    // 64-lane lex allreduce
        float ov = __shfl_xor(bv, s);
        int oi = __shfl_xor(bi, s);
        if (ov < bv || (ov == bv && oi < bi)) { bv = ov; bi = oi; }
    }
    if (lane == 0) out[r] = (float)bi;

    // fused gather: quantized[r] = es[bi]/max(us[bi],eps); 64 lanes x 4 floats
    float u = fmaxf(us[bi], VQ_EPS);
    f32x4 wv = *(const f32x4*)&es[bi * D_DIM + lane * 4];
    f32x4 o;
#pragma unroll
    for (int j = 0; j < 4; ++j) o[j] = wv[j] / u;         // IEEE div == np bitwise
    *(f32x4*)&out[N_ROWS + r * D_DIM + lane * 4] = o;
}

extern "C" void kernel_launch(void* const* d_in, const int* in_sizes, int n_in,
                              void* d_out, int out_size, void* d_ws, size_t ws_size,
                              hipStream_t stream) {
    const float* x = (const float*)d_in[0];               // [65536, 256]
    const float* es = (const float*)d_in[1];              // [2048, 256]
    const float* us = (const float*)d_in[2];              // [2048]
    float* out = (float*)d_out;

    char* w = (char*)d_ws;                                // total 45,359,104 B
    unsigned short* xswz = (unsigned short*)(w);                  // 33,554,432
    unsigned short* eswz = (unsigned short*)(w + 33554432);       //  1,048,576
    float* embed         = (float*)(w + 34603008);                //  2,097,152
    float* e2            = (float*)(w + 36700160);                //      8,192
    float* x2            = (float*)(w + 36708352);                //    262,144
    unsigned* keys1      = (unsigned*)(w + 36970496);             //  4,194,304
    unsigned* keys2      = (unsigned*)(w + 41164800);             //  4,194,304

    hipLaunchKernelGGL(prep_embed, dim3(2048), dim3(256), 0, stream, es, us, embed);
    hipLaunchKernelGGL(prep_swz_e, dim3(256), dim3(256), 0, stream, embed, eswz);
    hipLaunchKernelGGL(prep_e2, dim3(128), dim3(256), 0, stream, embed, e2);
    hipLaunchKernelGGL(prep_x, dim3(8192), dim3(256), 0, stream, x, xswz, x2);
    hipLaunchKernelGGL(vq_scan, dim3(8192), dim3(256), 0, stream,
                       xswz, eswz, e2, x2, keys1, keys2);
    hipLaunchKernelGGL(vq_rescore, dim3(16384), dim3(256), 0, stream,
                       x, embed, e2, x2, keys1, keys2, es, us, out);
}